// Round 4
// baseline (351.182 us; speedup 1.0000x reference)
//
#include <hip/hip_runtime.h>

#define N_REAL 16384
#define NLAB 64
#define NP 17408   /* N_REAL + 64*16 pad budget; 136 tiles of 128, fixed */
#define DIM 128
#define NSPLIT 8
#define TILES_TOTAL (NP / 128)                 /* 136 */
#define TPS (TILES_TOTAL / NSPLIT)             /* 17 col-tiles per split */
#define GHOSTS (NP - N_REAL)                   /* 1024 ghost columns */

typedef __bf16 bf16x8 __attribute__((ext_vector_type(8)));
typedef float f32x4 __attribute__((ext_vector_type(4)));
typedef unsigned short us8 __attribute__((ext_vector_type(8)));
typedef unsigned short us;
typedef unsigned int u32;

#define SCALE 2.8853900817779268f /* (1/T)*log2(e), T=0.5 */

__device__ inline float fast_exp2(float x) { return exp2f(x); }
__device__ inline float fast_log2(float x) { return log2f(x); }

__device__ inline us f2bf(float f) {  // fp32 -> bf16 RNE (finite)
  u32 u = __float_as_uint(f);
  u += 0x7fffu + ((u >> 16) & 1u);
  return (us)(u >> 16);
}
__device__ inline float bf2f(us x) {
  return __uint_as_float((u32)x << 16);
}

// global->LDS DMA, 16 B per lane; LDS dest = wave-uniform base + lane*16.
__device__ inline void gll16(const us* g, us* l) {
  __builtin_amdgcn_global_load_lds(
      (const __attribute__((address_space(1))) u32*)g,
      (__attribute__((address_space(3))) u32*)l, 16, 0, 0);
}

// ---------------- sort machinery (all tiny, once per call) ----------------

__global__ void init_k(int* slab_p, float* total, int* count) {
  int i = blockIdx.x * 256 + threadIdx.x;
  if (i < NP) slab_p[i] = -1;  // ghost marker
  if (i == 0) { *total = 0.f; *count = 0; }
}

// Histogram + 16-aligned prefix scan, single block.
__global__ void hist_scan(const int* __restrict__ labels, int* cntg, int* offp,
                          int* cursor) {
  __shared__ int h[NLAB];
  int tid = threadIdx.x;
  if (tid < NLAB) h[tid] = 0;
  __syncthreads();
  for (int i = tid; i < N_REAL; i += 256) atomicAdd(&h[labels[i]], 1);
  __syncthreads();
  if (tid == 0) {
    int o = 0;
    for (int l = 0; l < NLAB; ++l) {
      int c = h[l];
      cntg[l] = c;
      offp[l] = o;
      cursor[l] = o;
      o += (c + 15) & ~15;  // pad each label block to 16
    }
    offp[NLAB] = o;  // <= 17344; [o, NP) is ghost tail
  }
}

__global__ void scatter_k(const int* __restrict__ labels, int* cursor,
                          int* perm_p, int* slab_p) {
  int i = blockIdx.x * 256 + threadIdx.x;  // 64 blocks x 256 = N_REAL
  int l = labels[i];
  int p = atomicAdd(&cursor[l], 1);
  perm_p[p] = i;
  slab_p[p] = l;
}

// Gather rows in sorted order, convert to bf16, write fragment-linear global
// layout. Ghost slots -> zeros. eraw = raw (B operand), escal = pre-scaled (A).
// Granule g (within 128-row tile) = tc*256 + ks*64 + quad*16 + col16 holds
// row (tc*16+col16), dims ks*32+quad*8 .. +7.
__global__ __launch_bounds__(256) void preconv(
    const float* __restrict__ emb, const int* __restrict__ perm_p,
    const int* __restrict__ slab_p, us* __restrict__ eraw,
    us* __restrict__ escal) {
  const int tid = threadIdx.x;
  const size_t base = (size_t)blockIdx.x * 2048;  // granules per tile
#pragma unroll
  for (int i = 0; i < 8; ++i) {
    int g = i * 256 + tid;
    int col16 = g & 15;
    int quad = (g >> 4) & 3;
    int ks = (g >> 6) & 3;
    int tc = g >> 8;
    int slot = blockIdx.x * 128 + tc * 16 + col16;
    us8 r = {0, 0, 0, 0, 0, 0, 0, 0};
    us8 sc = {0, 0, 0, 0, 0, 0, 0, 0};
    if (slab_p[slot] >= 0) {
      const float* p = emb + (size_t)perm_p[slot] * DIM + ks * 32 + quad * 8;
      float4 a = *reinterpret_cast<const float4*>(p);
      float4 b = *reinterpret_cast<const float4*>(p + 4);
      r[0] = f2bf(a.x); r[1] = f2bf(a.y); r[2] = f2bf(a.z); r[3] = f2bf(a.w);
      r[4] = f2bf(b.x); r[5] = f2bf(b.y); r[6] = f2bf(b.z); r[7] = f2bf(b.w);
      sc[0] = f2bf(a.x * SCALE); sc[1] = f2bf(a.y * SCALE);
      sc[2] = f2bf(a.z * SCALE); sc[3] = f2bf(a.w * SCALE);
      sc[4] = f2bf(b.x * SCALE); sc[5] = f2bf(b.y * SCALE);
      sc[6] = f2bf(b.z * SCALE); sc[7] = f2bf(b.w * SCALE);
    }
    *reinterpret_cast<us8*>(eraw + (base + g) * 8) = r;
    *reinterpret_cast<us8*>(escal + (base + g) * 8) = sc;
  }
}

// ---------------- main fused kernel ----------------
// Sorted+padded space: every 16-row group is label-uniform, every positive
// range is tile-aligned -> pos mask is a wave-uniform scalar per (tr,tc).
// No diagonal handling here (corrected in reduce). Epilogue: exp2+add+fmac.
__global__ __launch_bounds__(256, 4) void cl_main(
    const us* __restrict__ eraw, const us* __restrict__ escal,
    const int* __restrict__ slab_p, const int* __restrict__ offp,
    float* __restrict__ ws_all, float* __restrict__ ws_pos) {
  __shared__ us lds[128 * DIM];  // 32 KB: A during preload, then B

  const int tid = threadIdx.x;
  const int lane = tid & 63;
  const int w = tid >> 6;  // wave 0..3, rows [w*32, w*32+32)
  const int quad = lane >> 4;
  const int r0 = blockIdx.x * 128;
  const int cs = blockIdx.y;

  // Stage pre-scaled A tile via DMA (fragment-linear, contiguous).
  {
    const us* g = escal + (size_t)blockIdx.x * (128 * DIM);
#pragma unroll
    for (int i = 0; i < 8; ++i) {
      int chunk = i * 4 + w;
      gll16(g + chunk * 512 + lane * 8, lds + chunk * 512);
    }
  }
  __syncthreads();

  // A-frag (verified): lane holds A[m=lane&15][k=quad*8+j].
  bf16x8 afrag[2][4];
#pragma unroll
  for (int tr = 0; tr < 2; ++tr)
#pragma unroll
    for (int ks = 0; ks < 4; ++ks)
      afrag[tr][ks] = *reinterpret_cast<const bf16x8*>(
          lds + ((w * 2 + tr) * 4 + ks) * 512 + lane * 8);

  // Wave-uniform positive ranges per 16-row group (ghost rows: lo=hi=0).
  int lo[2], hi[2];
#pragma unroll
  for (int tr = 0; tr < 2; ++tr) {
    int l = slab_p[r0 + w * 32 + tr * 16];
    lo[tr] = (l >= 0) ? offp[l] : 0;
    hi[tr] = (l >= 0) ? offp[l + 1] : 0;
  }

  float all_p[8], pos_p[8];
#pragma unroll
  for (int t = 0; t < 8; ++t) { all_p[t] = 0.f; pos_p[t] = 0.f; }

  for (int ct = 0; ct < TPS; ++ct) {
    const int ctg = cs * TPS + ct;
    __syncthreads();  // prior compute (or afrag preload) done
    {
      const us* g = eraw + (size_t)ctg * (128 * DIM);
#pragma unroll
      for (int i = 0; i < 8; ++i) {
        int chunk = i * 4 + w;
        gll16(g + chunk * 512 + lane * 8, lds + chunk * 512);
      }
    }
    __syncthreads();

#pragma unroll
    for (int tc = 0; tc < 8; ++tc) {
      bf16x8 bf[4];
#pragma unroll
      for (int ks = 0; ks < 4; ++ks)
        bf[ks] = *reinterpret_cast<const bf16x8*>(lds + (tc * 4 + ks) * 512 +
                                                  lane * 8);
      const int c = ctg * 128 + tc * 16;
#pragma unroll
      for (int tr = 0; tr < 2; ++tr) {
        f32x4 acc = {0.f, 0.f, 0.f, 0.f};
#pragma unroll
        for (int ks = 0; ks < 4; ++ks)
          acc = __builtin_amdgcn_mfma_f32_16x16x32_bf16(afrag[tr][ks], bf[ks],
                                                        acc, 0, 0, 0);
        const float m = (c >= lo[tr] && c < hi[tr]) ? 1.f : 0.f;
#pragma unroll
        for (int r = 0; r < 4; ++r) {
          float e = fast_exp2(acc[r]);  // C/D: col=lane&15, row=quad*4+r
          all_p[tr * 4 + r] += e;
          pos_p[tr * 4 + r] = fmaf(e, m, pos_p[tr * 4 + r]);
        }
      }
    }
  }

  // Reduce across the 16 col-lanes sharing each row; plain store per row.
#pragma unroll
  for (int t = 0; t < 8; ++t) {
    float a = all_p[t], p = pos_p[t];
#pragma unroll
    for (int m = 8; m >= 1; m >>= 1) {
      a += __shfl_xor(a, m, 64);
      p += __shfl_xor(p, m, 64);
    }
    if ((lane & 15) == 0) {
      int row_g = r0 + w * 32 + (t >> 2) * 16 + quad * 4 + (t & 3);
      ws_all[cs * NP + row_g] = a;
      ws_pos[cs * NP + row_g] = p;
    }
  }
}

// Per-row: sum splits, subtract ghost/pad/diagonal contributions, accumulate
// loss. Diagonal e_ii recomputed exactly from the bf16 operands (dot of the
// scaled and raw rows), so the hot loop needs no diagonal masking.
__global__ __launch_bounds__(256) void reduce_rows(
    const float* __restrict__ ws_all, const float* __restrict__ ws_pos,
    const int* __restrict__ slab_p, const int* __restrict__ offp,
    const int* __restrict__ cntg, const us* __restrict__ eraw,
    const us* __restrict__ escal, float* total, int* count) {
  __shared__ float s_t[256];
  __shared__ int s_c[256];
  const int tid = threadIdx.x;
  const int s = blockIdx.x * 256 + tid;
  float t = 0.f;
  int c = 0;
  int l = slab_p[s];
  if (l >= 0) {
    float a = 0.f, p = 0.f;
#pragma unroll
    for (int k = 0; k < NSPLIT; ++k) {
      a += ws_all[k * NP + s];
      p += ws_pos[k * NP + s];
    }
    // e_ii = exp2(escal_row . eraw_row)
    const int tile = s >> 7, rl = s & 127, tc = rl >> 4, c16 = rl & 15;
    const us* pa = escal + (size_t)tile * (128 * DIM);
    const us* pb = eraw + (size_t)tile * (128 * DIM);
    float dot = 0.f;
#pragma unroll
    for (int ks = 0; ks < 4; ++ks)
#pragma unroll
      for (int q = 0; q < 4; ++q) {
        int g = tc * 256 + ks * 64 + q * 16 + c16;
        us8 va = *reinterpret_cast<const us8*>(pa + g * 8);
        us8 vb = *reinterpret_cast<const us8*>(pb + g * 8);
#pragma unroll
        for (int j = 0; j < 8; ++j) dot = fmaf(bf2f(va[j]), bf2f(vb[j]), dot);
      }
    float eii = fast_exp2(dot);
    a -= (float)GHOSTS + eii;
    int pads = (offp[l + 1] - offp[l]) - cntg[l];
    p -= (float)pads + eii;
    if (cntg[l] > 1) {
      t = fast_log2(a) - fast_log2(p);
      c = 1;
    }
  }
  s_t[tid] = t;
  s_c[tid] = c;
  __syncthreads();
  for (int st = 128; st > 0; st >>= 1) {
    if (tid < st) {
      s_t[tid] += s_t[tid + st];
      s_c[tid] += s_c[tid + st];
    }
    __syncthreads();
  }
  if (tid == 0) {
    atomicAdd(total, s_t[0]);
    atomicAdd(count, s_c[0]);
  }
}

__global__ void final_k(const float* total, const int* count,
                        float* __restrict__ out) {
  if (threadIdx.x == 0)
    out[0] =
        (*count > 0) ? (*total) * 0.6931471805599453f / (float)(*count) : 0.f;
}

extern "C" void kernel_launch(void* const* d_in, const int* in_sizes, int n_in,
                              void* d_out, int out_size, void* d_ws,
                              size_t ws_size, hipStream_t stream) {
  const float* emb = (const float*)d_in[0];
  const int* labels = (const int*)d_in[1];

  char* w = (char*)d_ws;
  us* eraw = (us*)w;                      w += (size_t)NP * DIM * 2;
  us* escal = (us*)w;                     w += (size_t)NP * DIM * 2;
  float* ws_all = (float*)w;              w += (size_t)NSPLIT * NP * 4;
  float* ws_pos = (float*)w;              w += (size_t)NSPLIT * NP * 4;
  int* perm_p = (int*)w;                  w += NP * 4;
  int* slab_p = (int*)w;                  w += NP * 4;
  int* offp = (int*)w;                    w += (NLAB + 1) * 4;
  int* cntg = (int*)w;                    w += NLAB * 4;
  int* cursor = (int*)w;                  w += NLAB * 4;
  float* total = (float*)w;               w += 16;
  int* count = (int*)w;

  init_k<<<(NP + 255) / 256, 256, 0, stream>>>(slab_p, total, count);
  hist_scan<<<1, 256, 0, stream>>>(labels, cntg, offp, cursor);
  scatter_k<<<N_REAL / 256, 256, 0, stream>>>(labels, cursor, perm_p, slab_p);
  preconv<<<TILES_TOTAL, 256, 0, stream>>>(emb, perm_p, slab_p, eraw, escal);
  cl_main<<<dim3(TILES_TOTAL, NSPLIT), 256, 0, stream>>>(eraw, escal, slab_p,
                                                         offp, ws_all, ws_pos);
  reduce_rows<<<NP / 256, 256, 0, stream>>>(ws_all, ws_pos, slab_p, offp, cntg,
                                            eraw, escal, total, count);
  final_k<<<1, 64, 0, stream>>>(total, count, (float*)d_out);
}

// Round 5
// 313.069 us; speedup vs baseline: 1.1217x; 1.1217x over previous
//
#include <hip/hip_runtime.h>

#define N_REAL 16384
#define NLAB 64
#define NP 17408   /* N_REAL + 64*16 pad budget; 136 tiles of 128, fixed */
#define DIM 128
#define NSPLIT 8
#define TILES_TOTAL (NP / 128)                 /* 136 */
#define TPS (TILES_TOTAL / NSPLIT)             /* 17 col-tiles per split */
#define GHOSTS (NP - N_REAL)                   /* 1024 ghost columns */

typedef __bf16 bf16x8 __attribute__((ext_vector_type(8)));
typedef float f32x4 __attribute__((ext_vector_type(4)));
typedef unsigned short us8 __attribute__((ext_vector_type(8)));
typedef unsigned short us;
typedef unsigned int u32;

#define SCALE 2.8853900817779268f /* (1/T)*log2(e), T=0.5 */

__device__ inline float fast_exp2(float x) { return exp2f(x); }
__device__ inline float fast_log2(float x) { return log2f(x); }

__device__ inline us f2bf(float f) {  // fp32 -> bf16 RNE (finite)
  u32 u = __float_as_uint(f);
  u += 0x7fffu + ((u >> 16) & 1u);
  return (us)(u >> 16);
}
__device__ inline float bf2f(us x) {
  return __uint_as_float((u32)x << 16);
}

// global->LDS DMA, 16 B per lane; LDS dest = wave-uniform base + lane*16.
__device__ inline void gll16(const us* g, us* l) {
  __builtin_amdgcn_global_load_lds(
      (const __attribute__((address_space(1))) u32*)g,
      (__attribute__((address_space(3))) u32*)l, 16, 0, 0);
}

// ---------------- sort machinery (all tiny, once per call) ----------------

__global__ void init_k(int* slab_p, float* total, int* count) {
  int i = blockIdx.x * 256 + threadIdx.x;
  if (i < NP) slab_p[i] = -1;  // ghost marker
  if (i == 0) { *total = 0.f; *count = 0; }
}

// Histogram + 16-aligned prefix scan, single block.
__global__ void hist_scan(const int* __restrict__ labels, int* cntg, int* offp,
                          int* cursor) {
  __shared__ int h[NLAB];
  int tid = threadIdx.x;
  if (tid < NLAB) h[tid] = 0;
  __syncthreads();
  for (int i = tid; i < N_REAL; i += 256) atomicAdd(&h[labels[i]], 1);
  __syncthreads();
  if (tid == 0) {
    int o = 0;
    for (int l = 0; l < NLAB; ++l) {
      int c = h[l];
      cntg[l] = c;
      offp[l] = o;
      cursor[l] = o;
      o += (c + 15) & ~15;  // pad each label block to 16
    }
    offp[NLAB] = o;  // <= 17344; [o, NP) is ghost tail
  }
}

// Scatter with per-block LDS aggregation: 64 global atomics/block, not 256.
__global__ void scatter_k(const int* __restrict__ labels, int* cursor,
                          int* perm_p, int* slab_p) {
  __shared__ int lh[NLAB];
  __shared__ int base[NLAB];
  int tid = threadIdx.x;
  int i = blockIdx.x * 256 + tid;  // 64 blocks x 256 = N_REAL
  if (tid < NLAB) lh[tid] = 0;
  __syncthreads();
  int l = labels[i];
  int r = atomicAdd(&lh[l], 1);
  __syncthreads();
  if (tid < NLAB && lh[tid] > 0) base[tid] = atomicAdd(&cursor[tid], lh[tid]);
  __syncthreads();
  int p = base[l] + r;
  perm_p[p] = i;
  slab_p[p] = l;
}

// Gather rows in sorted order, convert to bf16, write fragment-linear global
// layout. Ghost slots -> zeros. eraw = raw (B operand), escal = pre-scaled (A).
// Granule g (within 128-row tile) = tc*256 + ks*64 + quad*16 + col16 holds
// row (tc*16+col16), dims ks*32+quad*8 .. +7.
__global__ __launch_bounds__(256) void preconv(
    const float* __restrict__ emb, const int* __restrict__ perm_p,
    const int* __restrict__ slab_p, us* __restrict__ eraw,
    us* __restrict__ escal) {
  const int tid = threadIdx.x;
  const size_t base = (size_t)blockIdx.x * 2048;  // granules per tile
#pragma unroll
  for (int i = 0; i < 8; ++i) {
    int g = i * 256 + tid;
    int col16 = g & 15;
    int quad = (g >> 4) & 3;
    int ks = (g >> 6) & 3;
    int tc = g >> 8;
    int slot = blockIdx.x * 128 + tc * 16 + col16;
    us8 r = {0, 0, 0, 0, 0, 0, 0, 0};
    us8 sc = {0, 0, 0, 0, 0, 0, 0, 0};
    if (slab_p[slot] >= 0) {
      const float* p = emb + (size_t)perm_p[slot] * DIM + ks * 32 + quad * 8;
      float4 a = *reinterpret_cast<const float4*>(p);
      float4 b = *reinterpret_cast<const float4*>(p + 4);
      r[0] = f2bf(a.x); r[1] = f2bf(a.y); r[2] = f2bf(a.z); r[3] = f2bf(a.w);
      r[4] = f2bf(b.x); r[5] = f2bf(b.y); r[6] = f2bf(b.z); r[7] = f2bf(b.w);
      sc[0] = f2bf(a.x * SCALE); sc[1] = f2bf(a.y * SCALE);
      sc[2] = f2bf(a.z * SCALE); sc[3] = f2bf(a.w * SCALE);
      sc[4] = f2bf(b.x * SCALE); sc[5] = f2bf(b.y * SCALE);
      sc[6] = f2bf(b.z * SCALE); sc[7] = f2bf(b.w * SCALE);
    }
    *reinterpret_cast<us8*>(eraw + (base + g) * 8) = r;
    *reinterpret_cast<us8*>(escal + (base + g) * 8) = sc;
  }
}

// ---------------- main fused kernel ----------------
// Sorted+padded space: pos mask is a wave-uniform scalar per (tr,tc-tile).
// Grid (NSPLIT, TILES): blockIdx.x = column-split cs. Linear block id =
// cs + 8*tile, and block->XCD = id % 8 = cs, so each XCD streams ONLY its own
// 544 KB B slice -> L2-resident (R4's 4.35 MB cyclic stream thrashed the 4 MB
// per-XCD L2: FETCH 18.7->280 MB). Zigzag tile order by tile parity hedges
// the XCD-mapping assumption (ping-pong beats cyclic LRU).
__global__ __launch_bounds__(256, 4) void cl_main(
    const us* __restrict__ eraw, const us* __restrict__ escal,
    const int* __restrict__ slab_p, const int* __restrict__ offp,
    float* __restrict__ ws_all, float* __restrict__ ws_pos) {
  __shared__ us lds[128 * DIM];  // 32 KB: A during preload, then B

  const int tid = threadIdx.x;
  const int lane = tid & 63;
  const int w = tid >> 6;  // wave 0..3, rows [w*32, w*32+32)
  const int quad = lane >> 4;
  const int cs = blockIdx.x;
  const int tile = blockIdx.y;
  const int r0 = tile * 128;

  // Stage pre-scaled A tile via DMA (fragment-linear, contiguous).
  {
    const us* g = escal + (size_t)tile * (128 * DIM);
#pragma unroll
    for (int i = 0; i < 8; ++i) {
      int chunk = i * 4 + w;
      gll16(g + chunk * 512 + lane * 8, lds + chunk * 512);
    }
  }
  __syncthreads();

  // A-frag (verified): lane holds A[m=lane&15][k=quad*8+j].
  bf16x8 afrag[2][4];
#pragma unroll
  for (int tr = 0; tr < 2; ++tr)
#pragma unroll
    for (int ks = 0; ks < 4; ++ks)
      afrag[tr][ks] = *reinterpret_cast<const bf16x8*>(
          lds + ((w * 2 + tr) * 4 + ks) * 512 + lane * 8);

  // Wave-uniform positive ranges per 16-row group (ghost rows: lo=hi=0).
  int lo[2], hi[2];
#pragma unroll
  for (int tr = 0; tr < 2; ++tr) {
    int l = slab_p[r0 + w * 32 + tr * 16];
    lo[tr] = (l >= 0) ? offp[l] : 0;
    hi[tr] = (l >= 0) ? offp[l + 1] : 0;
  }

  float all_p[8], pos_p[8];
#pragma unroll
  for (int t = 0; t < 8; ++t) { all_p[t] = 0.f; pos_p[t] = 0.f; }

  for (int ci = 0; ci < TPS; ++ci) {
    const int ct = (tile & 1) ? (TPS - 1 - ci) : ci;  // zigzag
    const int ctg = cs * TPS + ct;
    __syncthreads();  // prior compute (or afrag preload) done
    {
      const us* g = eraw + (size_t)ctg * (128 * DIM);
#pragma unroll
      for (int i = 0; i < 8; ++i) {
        int chunk = i * 4 + w;
        gll16(g + chunk * 512 + lane * 8, lds + chunk * 512);
      }
    }
    __syncthreads();

#pragma unroll
    for (int tc = 0; tc < 8; ++tc) {
      bf16x8 bf[4];
#pragma unroll
      for (int ks = 0; ks < 4; ++ks)
        bf[ks] = *reinterpret_cast<const bf16x8*>(lds + (tc * 4 + ks) * 512 +
                                                  lane * 8);
      const int c = ctg * 128 + tc * 16;
#pragma unroll
      for (int tr = 0; tr < 2; ++tr) {
        f32x4 acc = {0.f, 0.f, 0.f, 0.f};
#pragma unroll
        for (int ks = 0; ks < 4; ++ks)
          acc = __builtin_amdgcn_mfma_f32_16x16x32_bf16(afrag[tr][ks], bf[ks],
                                                        acc, 0, 0, 0);
        const float m = (c >= lo[tr] && c < hi[tr]) ? 1.f : 0.f;
#pragma unroll
        for (int r = 0; r < 4; ++r) {
          float e = fast_exp2(acc[r]);  // C/D: col=lane&15, row=quad*4+r
          all_p[tr * 4 + r] += e;
          pos_p[tr * 4 + r] = fmaf(e, m, pos_p[tr * 4 + r]);
        }
      }
    }
  }

  // Reduce across the 16 col-lanes sharing each row; plain store per row.
#pragma unroll
  for (int t = 0; t < 8; ++t) {
    float a = all_p[t], p = pos_p[t];
#pragma unroll
    for (int m = 8; m >= 1; m >>= 1) {
      a += __shfl_xor(a, m, 64);
      p += __shfl_xor(p, m, 64);
    }
    if ((lane & 15) == 0) {
      int row_g = r0 + w * 32 + (t >> 2) * 16 + quad * 4 + (t & 3);
      ws_all[cs * NP + row_g] = a;
      ws_pos[cs * NP + row_g] = p;
    }
  }
}

// Per-row: sum splits, subtract ghost/pad/diagonal contributions, accumulate
// loss. Diagonal e_ii recomputed exactly from the bf16 operands (dot of the
// scaled and raw rows), so the hot loop needs no diagonal masking.
__global__ __launch_bounds__(256) void reduce_rows(
    const float* __restrict__ ws_all, const float* __restrict__ ws_pos,
    const int* __restrict__ slab_p, const int* __restrict__ offp,
    const int* __restrict__ cntg, const us* __restrict__ eraw,
    const us* __restrict__ escal, float* total, int* count) {
  __shared__ float s_t[256];
  __shared__ int s_c[256];
  const int tid = threadIdx.x;
  const int s = blockIdx.x * 256 + tid;
  float t = 0.f;
  int c = 0;
  int l = slab_p[s];
  if (l >= 0) {
    float a = 0.f, p = 0.f;
#pragma unroll
    for (int k = 0; k < NSPLIT; ++k) {
      a += ws_all[k * NP + s];
      p += ws_pos[k * NP + s];
    }
    // e_ii = exp2(escal_row . eraw_row)
    const int tile = s >> 7, rl = s & 127, tc = rl >> 4, c16 = rl & 15;
    const us* pa = escal + (size_t)tile * (128 * DIM);
    const us* pb = eraw + (size_t)tile * (128 * DIM);
    float dot = 0.f;
#pragma unroll
    for (int ks = 0; ks < 4; ++ks)
#pragma unroll
      for (int q = 0; q < 4; ++q) {
        int g = tc * 256 + ks * 64 + q * 16 + c16;
        us8 va = *reinterpret_cast<const us8*>(pa + g * 8);
        us8 vb = *reinterpret_cast<const us8*>(pb + g * 8);
#pragma unroll
        for (int j = 0; j < 8; ++j) dot = fmaf(bf2f(va[j]), bf2f(vb[j]), dot);
      }
    float eii = fast_exp2(dot);
    a -= (float)GHOSTS + eii;
    int pads = (offp[l + 1] - offp[l]) - cntg[l];
    p -= (float)pads + eii;
    if (cntg[l] > 1) {
      t = fast_log2(a) - fast_log2(p);
      c = 1;
    }
  }
  s_t[tid] = t;
  s_c[tid] = c;
  __syncthreads();
  for (int st = 128; st > 0; st >>= 1) {
    if (tid < st) {
      s_t[tid] += s_t[tid + st];
      s_c[tid] += s_c[tid + st];
    }
    __syncthreads();
  }
  if (tid == 0) {
    atomicAdd(total, s_t[0]);
    atomicAdd(count, s_c[0]);
  }
}

__global__ void final_k(const float* total, const int* count,
                        float* __restrict__ out) {
  if (threadIdx.x == 0)
    out[0] =
        (*count > 0) ? (*total) * 0.6931471805599453f / (float)(*count) : 0.f;
}

extern "C" void kernel_launch(void* const* d_in, const int* in_sizes, int n_in,
                              void* d_out, int out_size, void* d_ws,
                              size_t ws_size, hipStream_t stream) {
  const float* emb = (const float*)d_in[0];
  const int* labels = (const int*)d_in[1];

  char* w = (char*)d_ws;
  us* eraw = (us*)w;                      w += (size_t)NP * DIM * 2;
  us* escal = (us*)w;                     w += (size_t)NP * DIM * 2;
  float* ws_all = (float*)w;              w += (size_t)NSPLIT * NP * 4;
  float* ws_pos = (float*)w;              w += (size_t)NSPLIT * NP * 4;
  int* perm_p = (int*)w;                  w += NP * 4;
  int* slab_p = (int*)w;                  w += NP * 4;
  int* offp = (int*)w;                    w += (NLAB + 1) * 4;
  int* cntg = (int*)w;                    w += NLAB * 4;
  int* cursor = (int*)w;                  w += NLAB * 4;
  float* total = (float*)w;               w += 16;
  int* count = (int*)w;

  init_k<<<(NP + 255) / 256, 256, 0, stream>>>(slab_p, total, count);
  hist_scan<<<1, 256, 0, stream>>>(labels, cntg, offp, cursor);
  scatter_k<<<N_REAL / 256, 256, 0, stream>>>(labels, cursor, perm_p, slab_p);
  preconv<<<TILES_TOTAL, 256, 0, stream>>>(emb, perm_p, slab_p, eraw, escal);
  cl_main<<<dim3(NSPLIT, TILES_TOTAL), 256, 0, stream>>>(eraw, escal, slab_p,
                                                         offp, ws_all, ws_pos);
  reduce_rows<<<NP / 256, 256, 0, stream>>>(ws_all, ws_pos, slab_p, offp, cntg,
                                            eraw, escal, total, count);
  final_k<<<1, 64, 0, stream>>>(total, count, (float*)d_out);
}

// Round 6
// 236.231 us; speedup vs baseline: 1.4866x; 1.3253x over previous
//
#include <hip/hip_runtime.h>

#define N_EMB 16384
#define DIM 128
#define NLAB 64
#define NSPLIT 8
#define CPS (N_EMB / NSPLIT) /* 2048 cols per split */
#define NCT (CPS / 128)      /* 16 col tiles per split */
#define NT (N_EMB / 128)     /* 128 row tiles */

typedef __bf16 bf16x8 __attribute__((ext_vector_type(8)));
typedef float f32x4 __attribute__((ext_vector_type(4)));
typedef unsigned short us8 __attribute__((ext_vector_type(8)));
typedef unsigned short us;
typedef unsigned int u32;

#define SCALE 2.8853900817779268f /* (1/T)*log2(e), T=0.5 */
#define LN2 0.6931471805599453f

__device__ inline us f2bf(float f) {  // fp32 -> bf16 RNE (finite)
  u32 u = __float_as_uint(f);
  u += 0x7fffu + ((u >> 16) & 1u);
  return (us)(u >> 16);
}

// global->LDS DMA, 16 B per lane; LDS dest = wave-uniform base + lane*16.
__device__ inline void gll16(const us* g, us* l) {
  __builtin_amdgcn_global_load_lds(
      (const __attribute__((address_space(1))) u32*)g,
      (__attribute__((address_space(3))) u32*)l, 16, 0, 0);
}

// ---------------- tiny prologue kernels ----------------

// Histogram + prefix scan (unpadded), single block. Also zeroes *total.
__global__ void hist_scan(const int* __restrict__ labels, int* cntg, int* offp,
                          int* cursor, float* total) {
  __shared__ int h[NLAB];
  int tid = threadIdx.x;
  if (tid < NLAB) h[tid] = 0;
  __syncthreads();
  for (int i = tid; i < N_EMB; i += 256) atomicAdd(&h[labels[i]], 1);
  __syncthreads();
  if (tid == 0) {
    int o = 0;
    for (int l = 0; l < NLAB; ++l) {
      cntg[l] = h[l];
      offp[l] = o;
      cursor[l] = o;
      o += h[l];
    }
    offp[NLAB] = o;
    *total = 0.f;
  }
}

// Scatter row indices grouped by label (LDS-aggregated atomics).
__global__ void scatter_k(const int* __restrict__ labels, int* cursor,
                          int* perm) {
  __shared__ int lh[NLAB];
  __shared__ int base[NLAB];
  int tid = threadIdx.x;
  int i = blockIdx.x * 256 + tid;  // 64 blocks x 256 = N_EMB
  if (tid < NLAB) lh[tid] = 0;
  __syncthreads();
  int l = labels[i];
  int r = atomicAdd(&lh[l], 1);
  __syncthreads();
  if (tid < NLAB && lh[tid] > 0) base[tid] = atomicAdd(&cursor[tid], lh[tid]);
  __syncthreads();
  perm[base[l] + r] = i;
}

// One-time fp32 -> bf16 conversion into fragment-linear global layout.
// Granule g (within a 128-row tile) = tc*256 + ks*64 + quad*16 + col16 holds
// row (tc*16+col16), dims ks*32+quad*8 .. +7. eraw = raw (B operand),
// escal = pre-scaled by SCALE (A operand).
__global__ __launch_bounds__(256) void preconv(const float* __restrict__ emb,
                                               us* __restrict__ eraw,
                                               us* __restrict__ escal) {
  const int tid = threadIdx.x;
  const size_t base = (size_t)blockIdx.x * 2048;  // granules per tile
#pragma unroll
  for (int i = 0; i < 8; ++i) {
    int g = i * 256 + tid;
    int col16 = g & 15;
    int quad = (g >> 4) & 3;
    int ks = (g >> 6) & 3;
    int tc = g >> 8;
    const float* p = emb + ((size_t)blockIdx.x * 128 + tc * 16 + col16) * DIM +
                     ks * 32 + quad * 8;
    float4 a = *reinterpret_cast<const float4*>(p);
    float4 b = *reinterpret_cast<const float4*>(p + 4);
    us8 r, sc;
    r[0] = f2bf(a.x); r[1] = f2bf(a.y); r[2] = f2bf(a.z); r[3] = f2bf(a.w);
    r[4] = f2bf(b.x); r[5] = f2bf(b.y); r[6] = f2bf(b.z); r[7] = f2bf(b.w);
    sc[0] = f2bf(a.x * SCALE); sc[1] = f2bf(a.y * SCALE);
    sc[2] = f2bf(a.z * SCALE); sc[3] = f2bf(a.w * SCALE);
    sc[4] = f2bf(b.x * SCALE); sc[5] = f2bf(b.y * SCALE);
    sc[6] = f2bf(b.z * SCALE); sc[7] = f2bf(b.w * SCALE);
    *reinterpret_cast<us8*>(eraw + (base + g) * 8) = r;
    *reinterpret_cast<us8*>(escal + (base + g) * 8) = sc;
  }
}

// ---------------- main fused kernel: all-sum only ----------------
// R3-proven memory structure: grid (NT, NSPLIT), B-stream = full 4.0 MB eraw
// per XCD (== L2 capacity, hits regardless of block->XCD mapping). No labels
// in the hot loop: epilogue is exp2 + add. Diagonal zeroed (wave-uniform).
__global__ __launch_bounds__(256, 4) void cl_main(
    const us* __restrict__ eraw, const us* __restrict__ escal,
    float* __restrict__ ws_all) {
  __shared__ us lds[128 * DIM];  // 32 KB: A during preload, then B

  const int tid = threadIdx.x;
  const int lane = tid & 63;
  const int w = tid >> 6;  // wave 0..3, rows [w*32, w*32+32)
  const int quad = lane >> 4;
  const int col16 = lane & 15;
  const int r0 = blockIdx.x * 128;
  const int cs = blockIdx.y;

  // Stage pre-scaled A tile via DMA (fragment-linear, contiguous).
  {
    const us* g = escal + (size_t)blockIdx.x * (128 * DIM);
#pragma unroll
    for (int i = 0; i < 8; ++i) {
      int chunk = i * 4 + w;
      gll16(g + chunk * 512 + lane * 8, lds + chunk * 512);
    }
  }
  __syncthreads();

  // A-frag (verified): lane holds A[m=lane&15][k=quad*8+j].
  bf16x8 afrag[2][4];
#pragma unroll
  for (int tr = 0; tr < 2; ++tr)
#pragma unroll
    for (int ks = 0; ks < 4; ++ks)
      afrag[tr][ks] = *reinterpret_cast<const bf16x8*>(
          lds + ((w * 2 + tr) * 4 + ks) * 512 + lane * 8);

  float all_p[8];
#pragma unroll
  for (int t = 0; t < 8; ++t) all_p[t] = 0.f;

  for (int ct = 0; ct < NCT; ++ct) {
    const int ctg = cs * NCT + ct;
    __syncthreads();  // prior compute (or afrag preload) done
    {
      const us* g = eraw + (size_t)ctg * (128 * DIM);
#pragma unroll
      for (int i = 0; i < 8; ++i) {
        int chunk = i * 4 + w;
        gll16(g + chunk * 512 + lane * 8, lds + chunk * 512);
      }
    }
    __syncthreads();

#pragma unroll
    for (int tc = 0; tc < 8; ++tc) {
      bf16x8 bf[4];
#pragma unroll
      for (int ks = 0; ks < 4; ++ks)
        bf[ks] = *reinterpret_cast<const bf16x8*>(lds + (tc * 4 + ks) * 512 +
                                                  lane * 8);
      const int c = ctg * 128 + tc * 16;
#pragma unroll
      for (int tr = 0; tr < 2; ++tr) {
        f32x4 acc = {0.f, 0.f, 0.f, 0.f};
#pragma unroll
        for (int ks = 0; ks < 4; ++ks)
          acc = __builtin_amdgcn_mfma_f32_16x16x32_bf16(afrag[tr][ks], bf[ks],
                                                        acc, 0, 0, 0);
        // C/D layout (verified): col = lane&15, row = quad*4 + r
        const bool diag = c == (r0 + w * 32 + tr * 16);
#pragma unroll
        for (int r = 0; r < 4; ++r) {
          float e = exp2f(acc[r]);
          if (diag && (quad * 4 + r) == col16) e = 0.f;  // exclude j == i
          all_p[tr * 4 + r] += e;
        }
      }
    }
  }

  // Reduce across the 16 col-lanes sharing each row; plain store per row.
#pragma unroll
  for (int t = 0; t < 8; ++t) {
    float a = all_p[t];
#pragma unroll
    for (int m = 8; m >= 1; m >>= 1) a += __shfl_xor(a, m, 64);
    if (col16 == 0) {
      int row_g = r0 + w * 32 + (t >> 2) * 16 + quad * 4 + (t & 3);
      ws_all[cs * N_EMB + row_g] = a;
    }
  }
}

// ---------------- positives pass: one block per label ----------------
// Within-label Gram via MFMA; A/B fragments gathered per-lane (16 B) from
// eraw through perm. ~1.6% of total pairs -> a few us for all 64 blocks.
__global__ __launch_bounds__(256) void pos_pass(const us* __restrict__ eraw,
                                                const int* __restrict__ perm,
                                                const int* __restrict__ offp,
                                                const int* __restrict__ cntg,
                                                float* __restrict__ pos) {
  const int l = blockIdx.x;
  const int off = offp[l];
  const int c = cntg[l];
  const int strips = (c + 15) >> 4;
  const int lane = threadIdx.x & 63;
  const int w = threadIdx.x >> 6;
  const int col16 = lane & 15;
  const int quad = lane >> 4;

  bf16x8 zerov;
#pragma unroll
  for (int j = 0; j < 8; ++j) zerov[j] = (__bf16)0.f;

  for (int i = w; i < strips; i += 4) {
    // Gather A frags for row strip i: lane holds row (i*16+col16).
    bf16x8 af[4] = {zerov, zerov, zerov, zerov};
    int rowA = i * 16 + col16;
    if (rowA < c) {
      int rg = perm[off + rowA];
      const us* pA = eraw + ((size_t)(rg >> 7) * 2048 +
                             ((rg & 127) >> 4) * 256 + quad * 16 + (rg & 15)) *
                                8;
#pragma unroll
      for (int ks = 0; ks < 4; ++ks)
        af[ks] = *reinterpret_cast<const bf16x8*>(pA + ks * 512);
    }
    float sum[4] = {0.f, 0.f, 0.f, 0.f};
    for (int j = 0; j < strips; ++j) {
      bf16x8 bf[4] = {zerov, zerov, zerov, zerov};
      int rowB = j * 16 + col16;
      if (rowB < c) {
        int rg = perm[off + rowB];
        const us* pB =
            eraw + ((size_t)(rg >> 7) * 2048 + ((rg & 127) >> 4) * 256 +
                    quad * 16 + (rg & 15)) *
                       8;
#pragma unroll
        for (int ks = 0; ks < 4; ++ks)
          bf[ks] = *reinterpret_cast<const bf16x8*>(pB + ks * 512);
      }
      f32x4 acc = {0.f, 0.f, 0.f, 0.f};
#pragma unroll
      for (int ks = 0; ks < 4; ++ks)
        acc = __builtin_amdgcn_mfma_f32_16x16x32_bf16(af[ks], bf[ks], acc, 0,
                                                      0, 0);
      const float gm = (rowB < c) ? 1.f : 0.f;  // ghost-column mask (per lane)
#pragma unroll
      for (int r = 0; r < 4; ++r) {
        float e = exp2f(acc[r] * SCALE);
        if (i == j && (quad * 4 + r) == col16) e = 0.f;  // diagonal
        sum[r] = fmaf(e, gm, sum[r]);
      }
    }
#pragma unroll
    for (int r = 0; r < 4; ++r) {
      float s = sum[r];
#pragma unroll
      for (int m = 8; m >= 1; m >>= 1) s += __shfl_xor(s, m, 64);
      if (col16 == 0) {
        int row = i * 16 + quad * 4 + r;
        if (row < c) pos[perm[off + row]] = s;
      }
    }
  }
}

// ---------------- reduction ----------------

__global__ __launch_bounds__(256) void reduce_rows(
    const float* __restrict__ ws_all, const float* __restrict__ pos,
    const int* __restrict__ labels, const int* __restrict__ cntg,
    float* total) {
  __shared__ float s_t[256];
  const int tid = threadIdx.x;
  const int row = blockIdx.x * 256 + tid;
  float a = 0.f;
#pragma unroll
  for (int k = 0; k < NSPLIT; ++k) a += ws_all[k * N_EMB + row];
  float t = 0.f;
  if (cntg[labels[row]] > 1) t = log2f(a) - log2f(pos[row]);
  s_t[tid] = t;
  __syncthreads();
  for (int st = 128; st > 0; st >>= 1) {
    if (tid < st) s_t[tid] += s_t[tid + st];
    __syncthreads();
  }
  if (tid == 0) atomicAdd(total, s_t[0]);
}

__global__ void final_k(const float* __restrict__ total,
                        const int* __restrict__ cntg,
                        float* __restrict__ out) {
  int tid = threadIdx.x;  // 64 threads, one wave
  int c = (tid < NLAB && cntg[tid] > 1) ? cntg[tid] : 0;
#pragma unroll
  for (int m = 32; m >= 1; m >>= 1) c += __shfl_xor(c, m, 64);
  if (tid == 0) out[0] = (c > 0) ? (*total) * LN2 / (float)c : 0.f;
}

extern "C" void kernel_launch(void* const* d_in, const int* in_sizes, int n_in,
                              void* d_out, int out_size, void* d_ws,
                              size_t ws_size, hipStream_t stream) {
  const float* emb = (const float*)d_in[0];
  const int* labels = (const int*)d_in[1];

  char* w = (char*)d_ws;
  us* eraw = (us*)w;            w += (size_t)N_EMB * DIM * 2;   // 4 MB
  us* escal = (us*)w;           w += (size_t)N_EMB * DIM * 2;   // 4 MB
  float* ws_all = (float*)w;    w += (size_t)NSPLIT * N_EMB * 4;
  float* pos = (float*)w;       w += (size_t)N_EMB * 4;
  int* perm = (int*)w;          w += (size_t)N_EMB * 4;
  int* offp = (int*)w;          w += (NLAB + 1) * 4;
  int* cntg = (int*)w;          w += NLAB * 4;
  int* cursor = (int*)w;        w += NLAB * 4;
  float* total = (float*)w;

  hist_scan<<<1, 256, 0, stream>>>(labels, cntg, offp, cursor, total);
  scatter_k<<<N_EMB / 256, 256, 0, stream>>>(labels, cursor, perm);
  preconv<<<NT, 256, 0, stream>>>(emb, eraw, escal);
  cl_main<<<dim3(NT, NSPLIT), 256, 0, stream>>>(eraw, escal, ws_all);
  pos_pass<<<NLAB, 256, 0, stream>>>(eraw, perm, offp, cntg, pos);
  reduce_rows<<<N_EMB / 256, 256, 0, stream>>>(ws_all, pos, labels, cntg,
                                               total);
  final_k<<<1, 64, 0, stream>>>(total, cntg, (float*)d_out);
}

// Round 7
// 167.652 us; speedup vs baseline: 2.0947x; 1.4091x over previous
//
#include <hip/hip_runtime.h>

#define N_EMB 16384
#define DIM 128
#define NLAB 64
#define NSPLIT 8
#define NCT (N_EMB / NSPLIT / 128) /* 16 col tiles per split */
#define NT (N_EMB / 128)           /* 128 row tiles */

typedef __bf16 bf16x8 __attribute__((ext_vector_type(8)));
typedef float f32x4 __attribute__((ext_vector_type(4)));
typedef unsigned short us8 __attribute__((ext_vector_type(8)));
typedef unsigned short us;
typedef unsigned int u32;

#define SCALE 2.8853900817779268f /* (1/T)*log2(e), T=0.5 */
#define LN2 0.6931471805599453f

// Raw transcendentals: v_exp_f32 / v_log_f32 (OCML exp2f adds fixup VALU).
__device__ inline float fexp2(float x) {
#if __has_builtin(__builtin_amdgcn_exp2f)
  return __builtin_amdgcn_exp2f(x);
#else
  return exp2f(x);
#endif
}
__device__ inline float flog2(float x) {
#if __has_builtin(__builtin_amdgcn_logf)
  return __builtin_amdgcn_logf(x);
#else
  return log2f(x);
#endif
}

__device__ inline us f2bf(float f) {  // fp32 -> bf16 RNE (finite)
  u32 u = __float_as_uint(f);
  u += 0x7fffu + ((u >> 16) & 1u);
  return (us)(u >> 16);
}

// global->LDS DMA, 16 B per lane; LDS dest = wave-uniform base + lane*16.
__device__ inline void gll16(const us* g, us* l) {
  __builtin_amdgcn_global_load_lds(
      (const __attribute__((address_space(1))) u32*)g,
      (__attribute__((address_space(3))) u32*)l, 16, 0, 0);
}

// ---------------- prologue kernels ----------------

__global__ void init_k(int* cntg, float* total) {
  if (threadIdx.x < NLAB) cntg[threadIdx.x] = 0;
  if (threadIdx.x == 0) *total = 0.f;
}

// fp32 -> bf16 fragment-linear conversion (raw + pre-scaled) FUSED with the
// label histogram (this block's 128 rows -> LDS -> one atomicAdd per bin).
// Granule g = tc*256 + ks*64 + quad*16 + col16 holds row (tc*16+col16),
// dims ks*32+quad*8 .. +7.
__global__ __launch_bounds__(256) void preconv(const float* __restrict__ emb,
                                               const int* __restrict__ labels,
                                               us* __restrict__ eraw,
                                               us* __restrict__ escal,
                                               int* __restrict__ cntg) {
  __shared__ int h[NLAB];
  const int tid = threadIdx.x;
  if (tid < NLAB) h[tid] = 0;
  __syncthreads();
  if (tid < 128) atomicAdd(&h[labels[blockIdx.x * 128 + tid]], 1);
  const size_t base = (size_t)blockIdx.x * 2048;  // granules per tile
#pragma unroll
  for (int i = 0; i < 8; ++i) {
    int g = i * 256 + tid;
    int col16 = g & 15;
    int quad = (g >> 4) & 3;
    int ks = (g >> 6) & 3;
    int tc = g >> 8;
    const float* p = emb + ((size_t)blockIdx.x * 128 + tc * 16 + col16) * DIM +
                     ks * 32 + quad * 8;
    float4 a = *reinterpret_cast<const float4*>(p);
    float4 b = *reinterpret_cast<const float4*>(p + 4);
    us8 r, sc;
    r[0] = f2bf(a.x); r[1] = f2bf(a.y); r[2] = f2bf(a.z); r[3] = f2bf(a.w);
    r[4] = f2bf(b.x); r[5] = f2bf(b.y); r[6] = f2bf(b.z); r[7] = f2bf(b.w);
    sc[0] = f2bf(a.x * SCALE); sc[1] = f2bf(a.y * SCALE);
    sc[2] = f2bf(a.z * SCALE); sc[3] = f2bf(a.w * SCALE);
    sc[4] = f2bf(b.x * SCALE); sc[5] = f2bf(b.y * SCALE);
    sc[6] = f2bf(b.z * SCALE); sc[7] = f2bf(b.w * SCALE);
    *reinterpret_cast<us8*>(eraw + (base + g) * 8) = r;
    *reinterpret_cast<us8*>(escal + (base + g) * 8) = sc;
  }
  __syncthreads();
  if (tid < NLAB && h[tid] > 0) atomicAdd(&cntg[tid], h[tid]);
}

// Exclusive prefix over 64 bins; writes offp and cursor. One wave.
__global__ void scan_k(const int* __restrict__ cntg, int* offp, int* cursor) {
  int tid = threadIdx.x;  // 64 threads
  int v = cntg[tid];
  int acc = 0;
#pragma unroll
  for (int k = 0; k < NLAB; ++k) {
    int ck = __shfl(v, k, 64);
    if (k < tid) acc += ck;
  }
  offp[tid] = acc;
  cursor[tid] = acc;
  if (tid == NLAB - 1) offp[NLAB] = acc + v;
}

// Scatter row indices grouped by label (LDS-aggregated atomics).
__global__ void scatter_k(const int* __restrict__ labels, int* cursor,
                          int* perm) {
  __shared__ int lh[NLAB];
  __shared__ int base[NLAB];
  int tid = threadIdx.x;
  int i = blockIdx.x * 256 + tid;  // 64 blocks x 256 = N_EMB
  if (tid < NLAB) lh[tid] = 0;
  __syncthreads();
  int l = labels[i];
  int r = atomicAdd(&lh[l], 1);
  __syncthreads();
  if (tid < NLAB && lh[tid] > 0) base[tid] = atomicAdd(&cursor[tid], lh[tid]);
  __syncthreads();
  perm[base[l] + r] = i;
}

// ---------------- main fused kernel: all-sum only ----------------
// R3/R6-proven memory structure (B stream = 4.0 MB eraw == per-XCD L2).
// 128-thread blocks, 64 rows per wave (tr=4): halves LDS B-reads per row
// vs 32-row waves. Epilogue = v_exp_f32 + add. Diagonal zeroed in-loop.
__global__ __launch_bounds__(128, 2) void cl_main(
    const us* __restrict__ eraw, const us* __restrict__ escal,
    float* __restrict__ ws_all) {
  __shared__ us lds[128 * DIM];  // 32 KB: A during preload, then B

  const int tid = threadIdx.x;
  const int lane = tid & 63;
  const int w = tid >> 6;  // wave 0..1, rows [w*64, w*64+64)
  const int quad = lane >> 4;
  const int col16 = lane & 15;
  const int r0 = blockIdx.x * 128;
  const int cs = blockIdx.y;

  // Stage pre-scaled A tile via DMA (fragment-linear, contiguous).
  {
    const us* g = escal + (size_t)blockIdx.x * (128 * DIM);
#pragma unroll
    for (int i = 0; i < 16; ++i) {
      int chunk = i * 2 + w;
      gll16(g + chunk * 512 + lane * 8, lds + chunk * 512);
    }
  }
  __syncthreads();

  // A-frags for this wave's 64 rows (A never re-read from LDS).
  bf16x8 afrag[4][4];
#pragma unroll
  for (int tr = 0; tr < 4; ++tr)
#pragma unroll
    for (int ks = 0; ks < 4; ++ks)
      afrag[tr][ks] = *reinterpret_cast<const bf16x8*>(
          lds + ((w * 4 + tr) * 4 + ks) * 512 + lane * 8);

  float all_p[16];
#pragma unroll
  for (int t = 0; t < 16; ++t) all_p[t] = 0.f;

  for (int ct = 0; ct < NCT; ++ct) {
    const int ctg = cs * NCT + ct;
    __syncthreads();  // prior compute (or afrag preload) done
    {
      const us* g = eraw + (size_t)ctg * (128 * DIM);
#pragma unroll
      for (int i = 0; i < 16; ++i) {
        int chunk = i * 2 + w;
        gll16(g + chunk * 512 + lane * 8, lds + chunk * 512);
      }
    }
    __syncthreads();

#pragma unroll
    for (int tc = 0; tc < 8; ++tc) {
      bf16x8 bf[4];
#pragma unroll
      for (int ks = 0; ks < 4; ++ks)
        bf[ks] = *reinterpret_cast<const bf16x8*>(lds + (tc * 4 + ks) * 512 +
                                                  lane * 8);
      const int c = ctg * 128 + tc * 16;
#pragma unroll
      for (int tr = 0; tr < 4; ++tr) {
        f32x4 acc = {0.f, 0.f, 0.f, 0.f};
#pragma unroll
        for (int ks = 0; ks < 4; ++ks)
          acc = __builtin_amdgcn_mfma_f32_16x16x32_bf16(afrag[tr][ks], bf[ks],
                                                        acc, 0, 0, 0);
        // C/D layout (verified): col = lane&15, row = quad*4 + r
        const bool diag = c == (r0 + w * 64 + tr * 16);
#pragma unroll
        for (int r = 0; r < 4; ++r) {
          float e = fexp2(acc[r]);
          if (diag && (quad * 4 + r) == col16) e = 0.f;  // exclude j == i
          all_p[tr * 4 + r] += e;
        }
      }
    }
  }

  // Reduce across the 16 col-lanes sharing each row; plain store per row.
#pragma unroll
  for (int t = 0; t < 16; ++t) {
    float a = all_p[t];
#pragma unroll
    for (int m = 8; m >= 1; m >>= 1) a += __shfl_xor(a, m, 64);
    if (col16 == 0) {
      int row_g = r0 + w * 64 + (t >> 2) * 16 + quad * 4 + (t & 3);
      ws_all[cs * N_EMB + row_g] = a;
    }
  }
}

// ---------------- positives + per-row loss ----------------
// Grid (NLAB, 20): block = (label l, strip i of 16 rows), grid-stride over
// strips for robustness. 4 waves split the j-strips; per-lane 16B gathers
// from eraw via perm (L2-resident). Each block finishes its rows: reads
// ws_all, computes log-diff, one atomicAdd(total) per block-strip.
__global__ __launch_bounds__(256) void pos_loss(
    const us* __restrict__ eraw, const float* __restrict__ ws_all,
    const int* __restrict__ perm, const int* __restrict__ offp,
    const int* __restrict__ cntg, float* __restrict__ total) {
  const int l = blockIdx.x;
  const int c = cntg[l];
  if (c < 2) return;  // no valid rows for this label
  const int off = offp[l];
  const int strips = (c + 15) >> 4;
  const int tid = threadIdx.x;
  const int lane = tid & 63;
  const int w = tid >> 6;
  const int col16 = lane & 15;
  const int quad = lane >> 4;

  __shared__ float sred[4][16];

  bf16x8 zerov;
#pragma unroll
  for (int j = 0; j < 8; ++j) zerov[j] = (__bf16)0.f;

  for (int i = blockIdx.y; i < strips; i += gridDim.y) {
    // A frags for row strip i: lane holds row (i*16+col16).
    bf16x8 af[4] = {zerov, zerov, zerov, zerov};
    int rowA = i * 16 + col16;
    if (rowA < c) {
      int rg = perm[off + rowA];
      const us* pA = eraw + ((size_t)(rg >> 7) * 2048 +
                             ((rg & 127) >> 4) * 256 + quad * 16 + (rg & 15)) *
                                8;
#pragma unroll
      for (int ks = 0; ks < 4; ++ks)
        af[ks] = *reinterpret_cast<const bf16x8*>(pA + ks * 512);
    }
    float sum[4] = {0.f, 0.f, 0.f, 0.f};
    for (int j = w; j < strips; j += 4) {
      bf16x8 bf[4] = {zerov, zerov, zerov, zerov};
      int rowB = j * 16 + col16;
      if (rowB < c) {
        int rg = perm[off + rowB];
        const us* pB =
            eraw + ((size_t)(rg >> 7) * 2048 + ((rg & 127) >> 4) * 256 +
                    quad * 16 + (rg & 15)) *
                       8;
#pragma unroll
        for (int ks = 0; ks < 4; ++ks)
          bf[ks] = *reinterpret_cast<const bf16x8*>(pB + ks * 512);
      }
      f32x4 acc = {0.f, 0.f, 0.f, 0.f};
#pragma unroll
      for (int ks = 0; ks < 4; ++ks)
        acc = __builtin_amdgcn_mfma_f32_16x16x32_bf16(af[ks], bf[ks], acc, 0,
                                                      0, 0);
      const float gm = (rowB < c) ? 1.f : 0.f;  // ghost-column mask
#pragma unroll
      for (int r = 0; r < 4; ++r) {
        float e = fexp2(acc[r] * SCALE);
        if (i == j && (quad * 4 + r) == col16) e = 0.f;  // diagonal
        sum[r] = fmaf(e, gm, sum[r]);
      }
    }
    // col-lane reduce, deposit per-wave partials.
#pragma unroll
    for (int r = 0; r < 4; ++r) {
      float s = sum[r];
#pragma unroll
      for (int m = 8; m >= 1; m >>= 1) s += __shfl_xor(s, m, 64);
      if (col16 == 0) sred[w][quad * 4 + r] = s;
    }
    __syncthreads();
    if (tid < 16) {
      int row = i * 16 + tid;
      float t = 0.f;
      if (row < c) {
        float p = sred[0][tid] + sred[1][tid] + sred[2][tid] + sred[3][tid];
        int rg = perm[off + row];
        float a = 0.f;
#pragma unroll
        for (int k = 0; k < NSPLIT; ++k) a += ws_all[k * N_EMB + rg];
        t = flog2(a) - flog2(p);
      }
#pragma unroll
      for (int m = 8; m >= 1; m >>= 1) t += __shfl_xor(t, m, 64);
      if (tid == 0) atomicAdd(total, t);
    }
    __syncthreads();  // sred reuse across grid-stride iterations
  }
}

__global__ void final_k(const float* __restrict__ total,
                        const int* __restrict__ cntg,
                        float* __restrict__ out) {
  int tid = threadIdx.x;  // 64 threads, one wave
  int c = (tid < NLAB && cntg[tid] > 1) ? cntg[tid] : 0;
#pragma unroll
  for (int m = 32; m >= 1; m >>= 1) c += __shfl_xor(c, m, 64);
  if (tid == 0) out[0] = (c > 0) ? (*total) * LN2 / (float)c : 0.f;
}

extern "C" void kernel_launch(void* const* d_in, const int* in_sizes, int n_in,
                              void* d_out, int out_size, void* d_ws,
                              size_t ws_size, hipStream_t stream) {
  const float* emb = (const float*)d_in[0];
  const int* labels = (const int*)d_in[1];

  char* w = (char*)d_ws;
  us* eraw = (us*)w;         w += (size_t)N_EMB * DIM * 2;  // 4 MB
  us* escal = (us*)w;        w += (size_t)N_EMB * DIM * 2;  // 4 MB
  float* ws_all = (float*)w; w += (size_t)NSPLIT * N_EMB * 4;
  int* perm = (int*)w;       w += (size_t)N_EMB * 4;
  int* offp = (int*)w;       w += (NLAB + 1) * 4;
  int* cntg = (int*)w;       w += NLAB * 4;
  int* cursor = (int*)w;     w += NLAB * 4;
  float* total = (float*)w;

  init_k<<<1, 64, 0, stream>>>(cntg, total);
  preconv<<<NT, 256, 0, stream>>>(emb, labels, eraw, escal, cntg);
  scan_k<<<1, 64, 0, stream>>>(cntg, offp, cursor);
  scatter_k<<<N_EMB / 256, 256, 0, stream>>>(labels, cursor, perm);
  cl_main<<<dim3(NT, NSPLIT), 128, 0, stream>>>(eraw, escal, ws_all);
  pos_loss<<<dim3(NLAB, 20), 256, 0, stream>>>(eraw, ws_all, perm, offp, cntg,
                                               total);
  final_k<<<1, 64, 0, stream>>>(total, cntg, (float*)d_out);
}

// Round 8
// 166.212 us; speedup vs baseline: 2.1129x; 1.0087x over previous
//
#include <hip/hip_runtime.h>

#define N_EMB 16384
#define DIM 128
#define NLAB 64
#define NSPLIT 8
#define NCT (N_EMB / NSPLIT / 128) /* 16 col tiles per split */
#define NT (N_EMB / 128)           /* 128 row tiles */
#define NP 17408                   /* padded sorted slots: 136 tiles */
#define NTP (NP / 128)             /* 136 */

typedef __bf16 bf16x8 __attribute__((ext_vector_type(8)));
typedef float f32x4 __attribute__((ext_vector_type(4)));
typedef unsigned short us8 __attribute__((ext_vector_type(8)));
typedef unsigned short us;
typedef unsigned int u32;

#define SCALE 2.8853900817779268f /* (1/T)*log2(e), T=0.5 */
#define LN2 0.6931471805599453f

// Raw transcendentals: v_exp_f32 / v_log_f32 (OCML exp2f adds fixup VALU).
__device__ inline float fexp2(float x) {
#if __has_builtin(__builtin_amdgcn_exp2f)
  return __builtin_amdgcn_exp2f(x);
#else
  return exp2f(x);
#endif
}
__device__ inline float flog2(float x) {
#if __has_builtin(__builtin_amdgcn_logf)
  return __builtin_amdgcn_logf(x);
#else
  return log2f(x);
#endif
}

__device__ inline us f2bf(float f) {  // fp32 -> bf16 RNE (finite)
  u32 u = __float_as_uint(f);
  u += 0x7fffu + ((u >> 16) & 1u);
  return (us)(u >> 16);
}

// global->LDS DMA, 16 B per lane; LDS dest = wave-uniform base + lane*16.
__device__ inline void gll16(const us* g, us* l) {
  __builtin_amdgcn_global_load_lds(
      (const __attribute__((address_space(1))) u32*)g,
      (__attribute__((address_space(3))) u32*)l, 16, 0, 0);
}

// ---------------- prologue kernels ----------------

__global__ void init_k(int* perm_p, int* cntg, float* total) {
  int i = blockIdx.x * 256 + threadIdx.x;
  if (i < NP) perm_p[i] = -1;  // ghost marker
  if (blockIdx.x == 0 && threadIdx.x < NLAB) cntg[threadIdx.x] = 0;
  if (blockIdx.x == 0 && threadIdx.x == 0) *total = 0.f;
}

// fp32 -> bf16 fragment-linear conversion (raw + pre-scaled) FUSED with the
// label histogram. Granule g = tc*256 + ks*64 + quad*16 + col16 holds row
// (tc*16+col16), dims ks*32+quad*8 .. +7.
__global__ __launch_bounds__(256) void preconv(const float* __restrict__ emb,
                                               const int* __restrict__ labels,
                                               us* __restrict__ eraw,
                                               us* __restrict__ escal,
                                               int* __restrict__ cntg) {
  __shared__ int h[NLAB];
  const int tid = threadIdx.x;
  if (tid < NLAB) h[tid] = 0;
  __syncthreads();
  if (tid < 128) atomicAdd(&h[labels[blockIdx.x * 128 + tid]], 1);
  const size_t base = (size_t)blockIdx.x * 2048;  // granules per tile
#pragma unroll
  for (int i = 0; i < 8; ++i) {
    int g = i * 256 + tid;
    int col16 = g & 15;
    int quad = (g >> 4) & 3;
    int ks = (g >> 6) & 3;
    int tc = g >> 8;
    const float* p = emb + ((size_t)blockIdx.x * 128 + tc * 16 + col16) * DIM +
                     ks * 32 + quad * 8;
    float4 a = *reinterpret_cast<const float4*>(p);
    float4 b = *reinterpret_cast<const float4*>(p + 4);
    us8 r, sc;
    r[0] = f2bf(a.x); r[1] = f2bf(a.y); r[2] = f2bf(a.z); r[3] = f2bf(a.w);
    r[4] = f2bf(b.x); r[5] = f2bf(b.y); r[6] = f2bf(b.z); r[7] = f2bf(b.w);
    sc[0] = f2bf(a.x * SCALE); sc[1] = f2bf(a.y * SCALE);
    sc[2] = f2bf(a.z * SCALE); sc[3] = f2bf(a.w * SCALE);
    sc[4] = f2bf(b.x * SCALE); sc[5] = f2bf(b.y * SCALE);
    sc[6] = f2bf(b.z * SCALE); sc[7] = f2bf(b.w * SCALE);
    *reinterpret_cast<us8*>(eraw + (base + g) * 8) = r;
    *reinterpret_cast<us8*>(escal + (base + g) * 8) = sc;
  }
  __syncthreads();
  if (tid < NLAB && h[tid] > 0) atomicAdd(&cntg[tid], h[tid]);
}

// 16-aligned exclusive prefix over 64 bins (padded sorted layout). One wave.
__global__ void scan_k(const int* __restrict__ cntg, int* offp, int* cursor) {
  int tid = threadIdx.x;  // 64 threads
  int pad = (cntg[tid] + 15) & ~15;
  int acc = 0;
#pragma unroll
  for (int k = 0; k < NLAB; ++k) {
    int ck = __shfl(pad, k, 64);
    if (k < tid) acc += ck;
  }
  offp[tid] = acc;
  cursor[tid] = acc;
}

// Scatter row indices into padded sorted slots (LDS-aggregated atomics).
__global__ void scatter_k(const int* __restrict__ labels, int* cursor,
                          int* perm_p) {
  __shared__ int lh[NLAB];
  __shared__ int base[NLAB];
  int tid = threadIdx.x;
  int i = blockIdx.x * 256 + tid;  // 64 blocks x 256 = N_EMB
  if (tid < NLAB) lh[tid] = 0;
  __syncthreads();
  int l = labels[i];
  int r = atomicAdd(&lh[l], 1);
  __syncthreads();
  if (tid < NLAB && lh[tid] > 0) base[tid] = atomicAdd(&cursor[tid], lh[tid]);
  __syncthreads();
  perm_p[base[l] + r] = i;
}

// Sorted padded fragment-linear bf16 copy (raw values); ghosts = 0.
// Coalesced stores; gather reads through perm_p.
__global__ __launch_bounds__(256) void esort_k(const float* __restrict__ emb,
                                               const int* __restrict__ perm_p,
                                               us* __restrict__ esort) {
  const int tid = threadIdx.x;
  const size_t base = (size_t)blockIdx.x * 2048;
#pragma unroll
  for (int i = 0; i < 8; ++i) {
    int g = i * 256 + tid;
    int col16 = g & 15;
    int quad = (g >> 4) & 3;
    int ks = (g >> 6) & 3;
    int tc = g >> 8;
    int slot = blockIdx.x * 128 + tc * 16 + col16;
    int rg = perm_p[slot];
    us8 r = {0, 0, 0, 0, 0, 0, 0, 0};
    if (rg >= 0) {
      const float* p = emb + (size_t)rg * DIM + ks * 32 + quad * 8;
      float4 a = *reinterpret_cast<const float4*>(p);
      float4 b = *reinterpret_cast<const float4*>(p + 4);
      r[0] = f2bf(a.x); r[1] = f2bf(a.y); r[2] = f2bf(a.z); r[3] = f2bf(a.w);
      r[4] = f2bf(b.x); r[5] = f2bf(b.y); r[6] = f2bf(b.z); r[7] = f2bf(b.w);
    }
    *reinterpret_cast<us8*>(esort + (base + g) * 8) = r;
  }
}

// ---------------- main fused kernel: all-sum only (unchanged from R7) -----
__global__ __launch_bounds__(128, 2) void cl_main(
    const us* __restrict__ eraw, const us* __restrict__ escal,
    float* __restrict__ ws_all) {
  __shared__ us lds[128 * DIM];  // 32 KB: A during preload, then B

  const int tid = threadIdx.x;
  const int lane = tid & 63;
  const int w = tid >> 6;  // wave 0..1, rows [w*64, w*64+64)
  const int quad = lane >> 4;
  const int col16 = lane & 15;
  const int r0 = blockIdx.x * 128;
  const int cs = blockIdx.y;

  {
    const us* g = escal + (size_t)blockIdx.x * (128 * DIM);
#pragma unroll
    for (int i = 0; i < 16; ++i) {
      int chunk = i * 2 + w;
      gll16(g + chunk * 512 + lane * 8, lds + chunk * 512);
    }
  }
  __syncthreads();

  bf16x8 afrag[4][4];
#pragma unroll
  for (int tr = 0; tr < 4; ++tr)
#pragma unroll
    for (int ks = 0; ks < 4; ++ks)
      afrag[tr][ks] = *reinterpret_cast<const bf16x8*>(
          lds + ((w * 4 + tr) * 4 + ks) * 512 + lane * 8);

  float all_p[16];
#pragma unroll
  for (int t = 0; t < 16; ++t) all_p[t] = 0.f;

  for (int ct = 0; ct < NCT; ++ct) {
    const int ctg = cs * NCT + ct;
    __syncthreads();
    {
      const us* g = eraw + (size_t)ctg * (128 * DIM);
#pragma unroll
      for (int i = 0; i < 16; ++i) {
        int chunk = i * 2 + w;
        gll16(g + chunk * 512 + lane * 8, lds + chunk * 512);
      }
    }
    __syncthreads();

#pragma unroll
    for (int tc = 0; tc < 8; ++tc) {
      bf16x8 bf[4];
#pragma unroll
      for (int ks = 0; ks < 4; ++ks)
        bf[ks] = *reinterpret_cast<const bf16x8*>(lds + (tc * 4 + ks) * 512 +
                                                  lane * 8);
      const int c = ctg * 128 + tc * 16;
#pragma unroll
      for (int tr = 0; tr < 4; ++tr) {
        f32x4 acc = {0.f, 0.f, 0.f, 0.f};
#pragma unroll
        for (int ks = 0; ks < 4; ++ks)
          acc = __builtin_amdgcn_mfma_f32_16x16x32_bf16(afrag[tr][ks], bf[ks],
                                                        acc, 0, 0, 0);
        const bool diag = c == (r0 + w * 64 + tr * 16);
#pragma unroll
        for (int r = 0; r < 4; ++r) {
          float e = fexp2(acc[r]);
          if (diag && (quad * 4 + r) == col16) e = 0.f;  // exclude j == i
          all_p[tr * 4 + r] += e;
        }
      }
    }
  }

#pragma unroll
  for (int t = 0; t < 16; ++t) {
    float a = all_p[t];
#pragma unroll
    for (int m = 8; m >= 1; m >>= 1) a += __shfl_xor(a, m, 64);
    if (col16 == 0) {
      int row_g = r0 + w * 64 + (t >> 2) * 16 + quad * 4 + (t & 3);
      ws_all[cs * N_EMB + row_g] = a;
    }
  }
}

// ---------------- positives + per-row loss (coalesced via esort) ----------
// Block = (label l, strip i of 16 sorted rows). All fragment loads are
// contiguous (base + lane*16) from the padded sorted copy; ghosts are zeros
// and masked. perm_p used only for the 16-lane ws_all lookup.
__global__ __launch_bounds__(256) void pos_loss(
    const us* __restrict__ esort, const float* __restrict__ ws_all,
    const int* __restrict__ perm_p, const int* __restrict__ offp,
    const int* __restrict__ cntg, float* __restrict__ total) {
  const int l = blockIdx.x;
  const int c = cntg[l];
  if (c < 2) return;  // no valid rows for this label
  const int off = offp[l];  // 16-aligned padded start
  const int strips = (c + 15) >> 4;
  const int tid = threadIdx.x;
  const int lane = tid & 63;
  const int w = tid >> 6;
  const int col16 = lane & 15;
  const int quad = lane >> 4;

  __shared__ float sred[4][16];

  for (int i = blockIdx.y; i < strips; i += gridDim.y) {
    const int sA = off + i * 16;  // strip start slot (16-aligned)
    const us* baseA = esort + ((size_t)(sA >> 7) * 2048 + ((sA & 127) >> 4) * 256) * 8;
    bf16x8 af[4];
#pragma unroll
    for (int ks = 0; ks < 4; ++ks)
      af[ks] = *reinterpret_cast<const bf16x8*>(baseA + (ks * 64 + lane) * 8);

    float sum[4] = {0.f, 0.f, 0.f, 0.f};
    for (int j = w; j < strips; j += 4) {
      const int sB = off + j * 16;
      const us* baseB =
          esort + ((size_t)(sB >> 7) * 2048 + ((sB & 127) >> 4) * 256) * 8;
      bf16x8 bf[4];
#pragma unroll
      for (int ks = 0; ks < 4; ++ks)
        bf[ks] = *reinterpret_cast<const bf16x8*>(baseB + (ks * 64 + lane) * 8);
      f32x4 acc = {0.f, 0.f, 0.f, 0.f};
#pragma unroll
      for (int ks = 0; ks < 4; ++ks)
        acc = __builtin_amdgcn_mfma_f32_16x16x32_bf16(af[ks], bf[ks], acc, 0,
                                                      0, 0);
      const float gm = (j * 16 + col16 < c) ? 1.f : 0.f;  // ghost cols
#pragma unroll
      for (int r = 0; r < 4; ++r) {
        float e = fexp2(acc[r] * SCALE);
        if (i == j && (quad * 4 + r) == col16) e = 0.f;  // diagonal
        sum[r] = fmaf(e, gm, sum[r]);
      }
    }
#pragma unroll
    for (int r = 0; r < 4; ++r) {
      float s = sum[r];
#pragma unroll
      for (int m = 8; m >= 1; m >>= 1) s += __shfl_xor(s, m, 64);
      if (col16 == 0) sred[w][quad * 4 + r] = s;
    }
    __syncthreads();
    if (tid < 16) {
      int row = i * 16 + tid;
      float t = 0.f;
      if (row < c) {
        float p = sred[0][tid] + sred[1][tid] + sred[2][tid] + sred[3][tid];
        int rg = perm_p[off + row];
        float a = 0.f;
#pragma unroll
        for (int k = 0; k < NSPLIT; ++k) a += ws_all[k * N_EMB + rg];
        t = flog2(a) - flog2(p);
      }
#pragma unroll
      for (int m = 8; m >= 1; m >>= 1) t += __shfl_xor(t, m, 64);
      if (tid == 0) atomicAdd(total, t);
    }
    __syncthreads();  // sred reuse across grid-stride iterations
  }
}

__global__ void final_k(const float* __restrict__ total,
                        const int* __restrict__ cntg,
                        float* __restrict__ out) {
  int tid = threadIdx.x;  // 64 threads, one wave
  int c = (tid < NLAB && cntg[tid] > 1) ? cntg[tid] : 0;
#pragma unroll
  for (int m = 32; m >= 1; m >>= 1) c += __shfl_xor(c, m, 64);
  if (tid == 0) out[0] = (c > 0) ? (*total) * LN2 / (float)c : 0.f;
}

extern "C" void kernel_launch(void* const* d_in, const int* in_sizes, int n_in,
                              void* d_out, int out_size, void* d_ws,
                              size_t ws_size, hipStream_t stream) {
  const float* emb = (const float*)d_in[0];
  const int* labels = (const int*)d_in[1];

  char* w = (char*)d_ws;
  us* eraw = (us*)w;         w += (size_t)N_EMB * DIM * 2;  // 4 MB
  us* escal = (us*)w;        w += (size_t)N_EMB * DIM * 2;  // 4 MB
  us* esort = (us*)w;        w += (size_t)NP * DIM * 2;     // 4.35 MB
  float* ws_all = (float*)w; w += (size_t)NSPLIT * N_EMB * 4;
  int* perm_p = (int*)w;     w += NP * 4;
  int* offp = (int*)w;       w += NLAB * 4;
  int* cntg = (int*)w;       w += NLAB * 4;
  int* cursor = (int*)w;     w += NLAB * 4;
  float* total = (float*)w;

  init_k<<<(NP + 255) / 256, 256, 0, stream>>>(perm_p, cntg, total);
  preconv<<<NT, 256, 0, stream>>>(emb, labels, eraw, escal, cntg);
  scan_k<<<1, 64, 0, stream>>>(cntg, offp, cursor);
  scatter_k<<<N_EMB / 256, 256, 0, stream>>>(labels, cursor, perm_p);
  esort_k<<<NTP, 256, 0, stream>>>(emb, perm_p, esort);
  cl_main<<<dim3(NT, NSPLIT), 128, 0, stream>>>(eraw, escal, ws_all);
  pos_loss<<<dim3(NLAB, 20), 256, 0, stream>>>(esort, ws_all, perm_p, offp,
                                               cntg, total);
  final_k<<<1, 64, 0, stream>>>(total, cntg, (float*)d_out);
}